// Round 6
// baseline (315.330 us; speedup 1.0000x reference)
//
#include <hip/hip_runtime.h>
#include <stdint.h>

// Fixed problem shape: outputs [8,16,384,384] fp32
#define B_ 8
#define D_ 16
#define H_ 384
#define W_ 384
constexpr int HW   = H_ * W_;     // 147456
constexpr int DHW  = D_ * HW;     // 2359296
constexpr int NCOL = B_ * HW;     // 1179648 columns
// Stratified run ids: id = run_idx * NCOL + column (runs concentrate in strata 0..2)
constexpr unsigned NRUN = (unsigned)NCOL * 8u;

constexpr float T_LOW  = 0.8f;
constexpr float T_HIGH = 0.92f;
constexpr unsigned DUST_MIN = 20u;
constexpr unsigned FLAGGED = 0xFFFFFFFEu;   // phase-1 root value: has strong voxel

constexpr int NBLK_QUAD = NCOL / 1024;  // 1152 (4 cols/thread kernels)

// local-UF patches: 32x32 cols, 256 threads = 4 cols/thread
// (thread t owns col lw=t&31 at rows lh, lh+8, lh+16, lh+24 where lh=t>>5).
// 32 floats/row = one whole 128B HBM line -> no cross-patch line sharing.
constexpr int PTW = 32, PTH = 32;
constexpr int PWB = W_ / PTW;             // 12
constexpr int PHB = H_ / PTH;             // 12
constexpr int NPATCH = B_ * PWB * PHB;    // 1152
constexpr int NXCD = 8;
constexpr int CHUNK = NPATCH / NXCD;      // 144

// boundary column-pairs between patches (half of 16x16 geometry)
constexpr int WPAIR_B = (PWB - 1) * H_;      // 4224
constexpr int HPAIR_B = (PHB - 1) * W_;      // 4224
constexpr int PAIR_B  = WPAIR_B + HPAIR_B;   // 8448
constexpr int NPAIRS  = B_ * PAIR_B;         // 67584

// ---------- global union-find over stratified z-run ids ----------
// parent[] : value < NRUN -> parent pointer; value >= NRUN -> root encoding.
// Phase 1 roots: 0xFFFFFFFF = no strong, 0xFFFFFFFE = has strong.
// Phase 2 roots: 0xFFFFFFFF - componentVoxelCount.
// Parents only ever decrease; halving stores only past-ancestor pointers (safe).
__device__ __forceinline__ unsigned gfind(unsigned* A, unsigned x) {
    for (;;) {
        unsigned p = A[x];
        if (p >= NRUN) return x;
        unsigned g = A[p];
        if (g >= NRUN) return p;
        A[x] = g;
        x = g;
    }
}

__device__ __forceinline__ unsigned groot_val(unsigned* A, unsigned x) {
    for (;;) {
        unsigned p = A[x];
        if (p >= NRUN) return p;
        unsigned g = A[p];
        if (g >= NRUN) return g;
        A[x] = g;
        x = g;
    }
}

// ensure the root of x's component is flagged (phase 1)
__device__ __forceinline__ void set_flag(unsigned* A, unsigned x) {
    unsigned r = gfind(A, x);
    for (;;) {
        unsigned old = atomicMin(&A[r], FLAGGED);
        if (old >= NRUN) return;
        r = gfind(A, old);
    }
}

// add cnt into the root encoding of x's component (phase 2).
__device__ __forceinline__ void add_count(unsigned* A, unsigned x, unsigned cnt) {
    unsigned r = gfind(A, x);
    for (;;) {
        unsigned old = A[r];
        if (old < NRUN) { r = gfind(A, old); continue; }
        if (atomicCAS(&A[r], old, old - cnt) == old) return;
    }
}

// union with flag propagation (phase 1)
__device__ __forceinline__ void gunite_flag(unsigned* A, unsigned a, unsigned b) {
    for (;;) {
        a = gfind(A, a);
        b = gfind(A, b);
        if (a == b) return;
        unsigned lo = a < b ? a : b;
        unsigned hi = a < b ? b : a;
        unsigned old = atomicMin(&A[hi], lo);
        if (old >= NRUN) {
            if (old == FLAGGED) set_flag(A, lo);
            return;
        }
        a = lo; b = old;
    }
}

// union with count propagation (phase 2)
__device__ __forceinline__ void gunite_cnt(unsigned* A, unsigned a, unsigned b) {
    for (;;) {
        a = gfind(A, a);
        b = gfind(A, b);
        if (a == b) return;
        unsigned lo = a < b ? a : b;
        unsigned hi = a < b ? b : a;
        unsigned old = atomicMin(&A[hi], lo);
        if (old >= NRUN) {
            unsigned cnt = 0xFFFFFFFFu - old;
            if (cnt) add_count(A, lo, cnt);
            return;
        }
        a = lo; b = old;
    }
}

// run index containing set bit p of mask m
__device__ __forceinline__ int runidx(unsigned m, int p) {
    unsigned starts = m & ~(m << 1);
    return __popc(starts & ((2u << p) - 1u)) - 1;
}

__device__ __forceinline__ int nruns(unsigned m) {
    return __popc(m & ~(m << 1));
}

// ---------- patch-local LDS union-find (ids: run_idx*1024 + local_col) ----------
// path-halving: stores past-ancestor values only (monotone chains -> safe)
__device__ __forceinline__ unsigned luf_find(unsigned* su, unsigned x) {
    for (;;) {
        unsigned p = su[x];
        if (p == x) return x;
        unsigned g = su[p];
        if (g == p) return p;
        su[x] = g;
        x = g;
    }
}

__device__ __forceinline__ void luf_union(unsigned* su, unsigned a, unsigned b) {
    for (;;) {
        a = luf_find(su, a);
        b = luf_find(su, b);
        if (a == b) return;
        unsigned lo = a < b ? a : b;
        unsigned hi = a < b ? b : a;
        unsigned old = atomicMin(&su[hi], lo);
        if (old == hi) return;
        a = lo; b = old;
    }
}

// intra-patch unions for local col lc against right (+1) and down (+32) neighbors
__device__ __forceinline__ void punions32(unsigned* su, const unsigned* sm,
                                          unsigned m, int lc, bool rok, bool dok) {
    if (!m) return;
    if (rok) {
        unsigned mB = sm[lc + 1];
        unsigned ov = m & mB;
        while (ov) {
            int p = __ffs(ov) - 1;
            luf_union(su, (unsigned)runidx(m, p) * 1024 + lc,
                          (unsigned)runidx(mB, p) * 1024 + lc + 1);
            ov &= ov + (1u << p);
        }
    }
    if (dok) {
        unsigned mB = sm[lc + 32];
        unsigned ov = m & mB;
        while (ov) {
            int p = __ffs(ov) - 1;
            luf_union(su, (unsigned)runidx(m, p) * 1024 + lc,
                          (unsigned)runidx(mB, p) * 1024 + lc + 32);
            ov &= ov + (1u << p);
        }
    }
}

// XCD-chunked block swizzle (verified r5: eliminates cross-XCD line duplication,
// and keeps loc1->loc2 producer/consumer data on the same XCD's L2)
__device__ __forceinline__ int swz_blk(int d) {
    return (d % NXCD) * CHUNK + d / NXCD;
}

// ---------------- kernels ----------------

// x -> thresholds in-reg -> patch-local UF on weak masks; roots carry strong
// flag; writes weak-mask array (u16) and all parent1 entries
__global__ __launch_bounds__(256) void k_loc1(const float* __restrict__ x,
                                              unsigned short* __restrict__ weakm,
                                              unsigned* __restrict__ parent1) {
    __shared__ unsigned sm[1024];
    __shared__ unsigned su[8192];          // 8 strata x 1024 cols
    __shared__ unsigned char sf[8192];     // strong flag per local id
    int blk = swz_blk(blockIdx.x);
    int b = blk / (PHB * PWB), pr = blk % (PHB * PWB);
    int h0 = (pr / PWB) * PTH, w0 = (pr % PWB) * PTW;
    int t = threadIdx.x;
    int lw = t & 31, lh = t >> 5;
    unsigned m[4], st[4];
    #pragma unroll
    for (int k = 0; k < 4; ++k) {
        int r = lh + 8 * k;
        const float* xp = x + (size_t)b * DHW + (size_t)(h0 + r) * W_ + (w0 + lw);
        float vz[16];
        #pragma unroll
        for (int z = 0; z < 16; ++z) vz[z] = xp[(size_t)z * HW];
        unsigned mm = 0, ss = 0;
        #pragma unroll
        for (int z = 0; z < 16; ++z) {
            mm |= (vz[z] >= T_LOW  ? 1u : 0u) << z;
            ss |= (vz[z] >= T_HIGH ? 1u : 0u) << z;
        }
        m[k] = mm; st[k] = ss;
        weakm[b * HW + (h0 + r) * W_ + (w0 + lw)] = (unsigned short)mm;
        sm[r * 32 + lw] = mm;
    }
    #pragma unroll
    for (int i = 0; i < 32; ++i) su[i * 256 + t] = i * 256 + t;
    unsigned* sf32 = (unsigned*)sf;
    #pragma unroll
    for (int i = 0; i < 8; ++i) sf32[i * 256 + t] = 0;
    __syncthreads();
    #pragma unroll
    for (int k = 0; k < 4; ++k) {
        int r = lh + 8 * k, lc = r * 32 + lw;
        punions32(su, sm, m[k], lc, lw < 31, r < 31);
    }
    __syncthreads();
    // strong-flag pass: iterate strong bits; group-clear dedupes within a run
    #pragma unroll
    for (int k = 0; k < 4; ++k) {
        unsigned ov = st[k];
        if (!ov) continue;
        int lc = (lh + 8 * k) * 32 + lw;
        while (ov) {
            int p = __ffs(ov) - 1;
            sf[luf_find(su, (unsigned)runidx(m[k], p) * 1024 + lc)] = 1;
            ov &= ov + (1u << p);
        }
    }
    __syncthreads();
    #pragma unroll
    for (int k = 0; k < 4; ++k) {
        int r = lh + 8 * k, lc = r * 32 + lw;
        int c = b * HW + (h0 + r) * W_ + (w0 + lw);
        int nr = nruns(m[k]);
        for (int i = 0; i < nr; ++i) {
            unsigned lid = (unsigned)i * 1024 + lc;
            unsigned lr  = luf_find(su, lid);
            unsigned gid = (unsigned)i * NCOL + c;
            if (lr == lid) parent1[gid] = sf[lid] ? FLAGGED : 0xFFFFFFFFu;
            else {
                unsigned tt = lr & 1023u, ss2 = lr >> 10;
                parent1[gid] = ss2 * NCOL +
                    (unsigned)(b * HW + (h0 + (int)(tt >> 5)) * W_ + (w0 + (int)(tt & 31)));
            }
        }
    }
}

// cross-patch boundary unions with flag propagation (weak).
// Serial-per-pair mapping: 64 lanes process 64 pairs' unions in lockstep.
__global__ __launch_bounds__(256) void k_bnd1(const unsigned short* __restrict__ weakm,
                                              unsigned* parent1) {
    int e = blockIdx.x * 256 + threadIdx.x;
    if (e >= NPAIRS) return;
    int b = e / PAIR_B, r = e % PAIR_B;
    int cA, cB;
    if (r < WPAIR_B) {
        int h = r / (PWB - 1), wi = r % (PWB - 1);
        cA = b * HW + h * W_ + wi * PTW + (PTW - 1);
        cB = cA + 1;
    } else {
        r -= WPAIR_B;
        int hi = r / W_, w = r % W_;
        cA = b * HW + (hi * PTH + (PTH - 1)) * W_ + w;
        cB = cA + W_;
    }
    unsigned mA = weakm[cA];
    unsigned mB = weakm[cB];
    unsigned ov = mA & mB;
    while (ov) {
        int p = __ffs(ov) - 1;
        gunite_flag(parent1, (unsigned)runidx(mA, p) * NCOL + cA,
                             (unsigned)runidx(mB, p) * NCOL + cB);
        ov &= ov + (1u << p);
    }
}

// hysteresis (prefetched first-hop chase) + z-closing + patch-local UF on
// closed masks with per-local-root voxel counts; writes closed + parent2
__global__ __launch_bounds__(256) void k_loc2(const unsigned short* __restrict__ weakm,
                                              unsigned* parent1,
                                              unsigned short* __restrict__ closed,
                                              unsigned* __restrict__ parent2) {
    __shared__ unsigned sm[1024];
    __shared__ unsigned su[6144];   // closed masks: <=6 runs/col (gaps >=2)
    __shared__ unsigned sc[6144];
    int blk = swz_blk(blockIdx.x);
    int b = blk / (PHB * PWB), pr = blk % (PHB * PWB);
    int h0 = (pr / PWB) * PTH, w0 = (pr % PWB) * PTW;
    int t = threadIdx.x;
    int lw = t & 31, lh = t >> 5;
    unsigned wk[4];
    int c_[4];
    #pragma unroll
    for (int k = 0; k < 4; ++k) {
        int r = lh + 8 * k;
        c_[k] = b * HW + (h0 + r) * W_ + (w0 + lw);
        wk[k] = weakm[c_[k]];
    }
    // prefetch first hop for up to 6 runs per col, all 4 cols (24 independent loads)
    unsigned pv[4][6];
    #pragma unroll
    for (int k = 0; k < 4; ++k) {
        int nrw = nruns(wk[k]);
        #pragma unroll
        for (int i = 0; i < 6; ++i)
            if (i < nrw) pv[k][i] = parent1[(unsigned)i * NCOL + c_[k]];
    }
    unsigned ero[4];
    #pragma unroll
    for (int k = 0; k < 4; ++k) {
        unsigned m = 0;
        unsigned rem = wk[k]; int idx = 0;
        while (rem) {
            int p = __ffs(rem) - 1;
            unsigned tt = rem >> p;
            int len = __ffs(~tt) - 1;
            unsigned runmask = ((1u << len) - 1u) << p;
            unsigned rv;
            if (idx < 6) { unsigned v = pv[k][idx]; rv = (v >= NRUN) ? v : groot_val(parent1, v); }
            else rv = groot_val(parent1, (unsigned)idx * NCOL + c_[k]);
            if (rv == FLAGGED) m |= runmask;
            rem &= ~runmask; ++idx;
        }
        // z-closing: dilate (OOB = background), erode (OOB = foreground)
        unsigned dil = (m | (m << 1) | (m >> 1)) & 0xFFFFu;
        unsigned e = dil & ((dil << 1) | 1u) & ((dil >> 1) | 0x8000u);
        ero[k] = e;
        closed[c_[k]] = (unsigned short)e;
        sm[(lh + 8 * k) * 32 + lw] = e;
    }
    #pragma unroll
    for (int i = 0; i < 24; ++i) su[i * 256 + t] = i * 256 + t;
    #pragma unroll
    for (int i = 0; i < 24; ++i) sc[i * 256 + t] = 0;
    __syncthreads();
    #pragma unroll
    for (int k = 0; k < 4; ++k) {
        int r = lh + 8 * k, lc = r * 32 + lw;
        punions32(su, sm, ero[k], lc, lw < 31, r < 31);
    }
    __syncthreads();
    #pragma unroll
    for (int k = 0; k < 4; ++k) {
        int lc = (lh + 8 * k) * 32 + lw;
        unsigned rem = ero[k]; int idx = 0;
        while (rem) {
            int p = __ffs(rem) - 1;
            unsigned tt = rem >> p;
            int len = __ffs(~tt) - 1;
            unsigned runmask = ((1u << len) - 1u) << p;
            atomicAdd(&sc[luf_find(su, (unsigned)idx * 1024 + lc)], (unsigned)len);
            rem &= ~runmask; ++idx;
        }
    }
    __syncthreads();
    #pragma unroll
    for (int k = 0; k < 4; ++k) {
        int r = lh + 8 * k, lc = r * 32 + lw;
        int c = c_[k];
        int nr = nruns(ero[k]);
        for (int i = 0; i < nr; ++i) {
            unsigned lid = (unsigned)i * 1024 + lc;
            unsigned lr  = luf_find(su, lid);
            unsigned gid = (unsigned)i * NCOL + c;
            if (lr == lid) parent2[gid] = 0xFFFFFFFFu - sc[lid];
            else {
                unsigned tt = lr & 1023u, ss2 = lr >> 10;
                parent2[gid] = ss2 * NCOL +
                    (unsigned)(b * HW + (h0 + (int)(tt >> 5)) * W_ + (w0 + (int)(tt & 31)));
            }
        }
    }
}

// cross-patch boundary unions with count propagation (closed)
__global__ __launch_bounds__(256) void k_bnd2(const unsigned short* __restrict__ closed,
                                              unsigned* parent2) {
    int e = blockIdx.x * 256 + threadIdx.x;
    if (e >= NPAIRS) return;
    int b = e / PAIR_B, r = e % PAIR_B;
    int cA, cB;
    if (r < WPAIR_B) {
        int h = r / (PWB - 1), wi = r % (PWB - 1);
        cA = b * HW + h * W_ + wi * PTW + (PTW - 1);
        cB = cA + 1;
    } else {
        r -= WPAIR_B;
        int hi = r / W_, w = r % W_;
        cA = b * HW + (hi * PTH + (PTH - 1)) * W_ + w;
        cB = cA + W_;
    }
    unsigned mA = closed[cA];
    unsigned mB = closed[cB];
    unsigned ov = mA & mB;
    while (ov) {
        int p = __ffs(ov) - 1;
        gunite_cnt(parent2, (unsigned)runidx(mA, p) * NCOL + cA,
                            (unsigned)runidx(mB, p) * NCOL + cB);
        ov &= ov + (1u << p);
    }
}

// keep components with size >= DUST_MIN; write 0/1 float (4 cols/thread)
__global__ __launch_bounds__(256) void k_out(const unsigned short* __restrict__ closed,
                                             unsigned* parent2,
                                             float* __restrict__ out) {
    int q = blockIdx.x * 256 + threadIdx.x;
    int c0 = q * 4;
    int b = c0 / HW, off = c0 - b * HW;
    ushort4 cc4 = *(const ushort4*)(closed + c0);
    unsigned fg[4] = {cc4.x, cc4.y, cc4.z, cc4.w};
    // closed masks have inter-run gaps >= 2 (erosion), so nruns <= 6:
    // prefetching 6 first-hops covers every run; fallback kept as guard only.
    unsigned pv[4][6];
    int nr[4];
    #pragma unroll
    for (int j = 0; j < 4; ++j) {
        nr[j] = nruns(fg[j]);
        #pragma unroll
        for (int i = 0; i < 6; ++i)
            if (i < nr[j]) pv[j][i] = parent2[(unsigned)i * NCOL + (c0 + j)];
    }
    unsigned keep[4];
    #pragma unroll
    for (int j = 0; j < 4; ++j) {
        int c = c0 + j;
        unsigned k = 0;
        unsigned rem = fg[j]; int idx = 0;
        while (rem) {
            int p = __ffs(rem) - 1;
            unsigned tt = rem >> p;
            int len = __ffs(~tt) - 1;
            unsigned runmask = ((1u << len) - 1u) << p;
            unsigned rv;
            if (idx < 6) { unsigned v = pv[j][idx]; rv = (v >= NRUN) ? v : groot_val(parent2, v); }
            else rv = groot_val(parent2, (unsigned)idx * NCOL + c);
            if (0xFFFFFFFFu - rv >= DUST_MIN) k |= runmask;
            rem &= ~runmask; ++idx;
        }
        keep[j] = k;
    }
    float* op = out + (size_t)b * DHW + off;
    #pragma unroll
    for (int z = 0; z < D_; ++z) {
        *(float4*)(op + (size_t)z * HW) =
            make_float4((keep[0] >> z) & 1u ? 1.0f : 0.0f,
                        (keep[1] >> z) & 1u ? 1.0f : 0.0f,
                        (keep[2] >> z) & 1u ? 1.0f : 0.0f,
                        (keep[3] >> z) & 1u ? 1.0f : 0.0f);
    }
}

extern "C" void kernel_launch(void* const* d_in, const int* in_sizes, int n_in,
                              void* d_out, int out_size, void* d_ws, size_t ws_size,
                              hipStream_t stream) {
    const float* x = (const float*)d_in[0];
    float* out = (float*)d_out;

    // ws: parent1 [NRUN u32] | parent2 [NRUN u32] | weak [NCOL u16] | closed [NCOL u16]
    const size_t sz_parent = (size_t)NRUN * 4;
    const size_t sz_mask   = (size_t)NCOL * 2;
    if (ws_size < 2 * sz_parent + 2 * sz_mask) return;
    char* ws = (char*)d_ws;
    unsigned*       parent1 = (unsigned*)ws;
    unsigned*       parent2 = (unsigned*)(ws + sz_parent);
    unsigned short* weakm   = (unsigned short*)(ws + 2 * sz_parent);
    unsigned short* closed  = (unsigned short*)(ws + 2 * sz_parent + sz_mask);

    dim3 blk(256);
    dim3 grdL(NPATCH), grdB((NPAIRS + 255) / 256), grdQ(NBLK_QUAD);

    // ---- phase 1: weak-run CCL with inline strong flags ----
    k_loc1<<<grdL, blk, 0, stream>>>(x, weakm, parent1);
    k_bnd1<<<grdB, blk, 0, stream>>>(weakm, parent1);

    // ---- phase 2: hysteresis+closing, closed-run CCL with inline counts ----
    k_loc2<<<grdL, blk, 0, stream>>>(weakm, parent1, closed, parent2);
    k_bnd2<<<grdB, blk, 0, stream>>>(closed, parent2);
    k_out<<<grdQ, blk, 0, stream>>>(closed, parent2, out);
}

// Round 7
// 258.426 us; speedup vs baseline: 1.2202x; 1.2202x over previous
//
#include <hip/hip_runtime.h>
#include <stdint.h>

// Fixed problem shape: outputs [8,16,384,384] fp32
#define B_ 8
#define D_ 16
#define H_ 384
#define W_ 384
constexpr int HW   = H_ * W_;     // 147456
constexpr int DHW  = D_ * HW;     // 2359296
constexpr int NCOL = B_ * HW;     // 1179648 columns
// Stratified run ids: id = run_idx * NCOL + column (runs concentrate in strata 0..2)
constexpr unsigned NRUN = (unsigned)NCOL * 8u;

constexpr float T_LOW  = 0.8f;
constexpr float T_HIGH = 0.92f;
constexpr unsigned DUST_MIN = 20u;
constexpr unsigned FLAGGED = 0xFFFFFFFEu;   // phase-1 root value: has strong voxel

constexpr int NBLK_QUAD = NCOL / 1024;  // 1152 (4 cols/thread kernels)

// local-UF patches: 32x16 cols, 256 threads = 2 cols/thread
// (thread t owns col lw=t&31 at rows lh and lh+8, lh=t>>5).
// 32 floats/row = whole 128B HBM lines -> no cross-patch line sharing.
constexpr int PTW = 32, PTH = 16;
constexpr int PWB = W_ / PTW;             // 12
constexpr int PHB = H_ / PTH;             // 24
constexpr int NPATCH = B_ * PWB * PHB;    // 2304
constexpr int NXCD = 8;
constexpr int CHUNK = NPATCH / NXCD;      // 288 = exactly one batch's patches

// boundary column-pairs between patches (-26% vs 16x16)
constexpr int WPAIR_B = (PWB - 1) * H_;      // 4224
constexpr int HPAIR_B = (PHB - 1) * W_;      // 8832
constexpr int PAIR_B  = WPAIR_B + HPAIR_B;   // 13056
constexpr int NPAIRS  = B_ * PAIR_B;         // 104448
constexpr int NBLK_BND = NPAIRS / 256;       // 408 (exact)
constexpr int CHUNK_BND = NBLK_BND / NXCD;   // 51 = exactly one batch's pair-blocks

// local ids: run_idx * 512 + local_col (local_col = r*32+lw, r in 0..15)
constexpr int LCOLS = PTW * PTH;          // 512

// ---------- global union-find over stratified z-run ids ----------
// parent[] : value < NRUN -> parent pointer; value >= NRUN -> root encoding.
// Phase 1 roots: 0xFFFFFFFF = no strong, 0xFFFFFFFE = has strong.
// Phase 2 roots: 0xFFFFFFFF - componentVoxelCount.
// Parents only ever decrease; halving stores only past-ancestor pointers (safe).
__device__ __forceinline__ unsigned gfind(unsigned* A, unsigned x) {
    for (;;) {
        unsigned p = A[x];
        if (p >= NRUN) return x;
        unsigned g = A[p];
        if (g >= NRUN) return p;
        A[x] = g;
        x = g;
    }
}

__device__ __forceinline__ unsigned groot_val(unsigned* A, unsigned x) {
    for (;;) {
        unsigned p = A[x];
        if (p >= NRUN) return p;
        unsigned g = A[p];
        if (g >= NRUN) return g;
        A[x] = g;
        x = g;
    }
}

// ensure the root of x's component is flagged (phase 1)
__device__ __forceinline__ void set_flag(unsigned* A, unsigned x) {
    unsigned r = gfind(A, x);
    for (;;) {
        unsigned old = atomicMin(&A[r], FLAGGED);
        if (old >= NRUN) return;
        r = gfind(A, old);
    }
}

// add cnt into the root encoding of x's component (phase 2).
__device__ __forceinline__ void add_count(unsigned* A, unsigned x, unsigned cnt) {
    unsigned r = gfind(A, x);
    for (;;) {
        unsigned old = A[r];
        if (old < NRUN) { r = gfind(A, old); continue; }
        if (atomicCAS(&A[r], old, old - cnt) == old) return;
    }
}

// union with flag propagation (phase 1)
__device__ __forceinline__ void gunite_flag(unsigned* A, unsigned a, unsigned b) {
    for (;;) {
        a = gfind(A, a);
        b = gfind(A, b);
        if (a == b) return;
        unsigned lo = a < b ? a : b;
        unsigned hi = a < b ? b : a;
        unsigned old = atomicMin(&A[hi], lo);
        if (old >= NRUN) {
            if (old == FLAGGED) set_flag(A, lo);
            return;
        }
        a = lo; b = old;
    }
}

// union with count propagation (phase 2)
__device__ __forceinline__ void gunite_cnt(unsigned* A, unsigned a, unsigned b) {
    for (;;) {
        a = gfind(A, a);
        b = gfind(A, b);
        if (a == b) return;
        unsigned lo = a < b ? a : b;
        unsigned hi = a < b ? b : a;
        unsigned old = atomicMin(&A[hi], lo);
        if (old >= NRUN) {
            unsigned cnt = 0xFFFFFFFFu - old;
            if (cnt) add_count(A, lo, cnt);
            return;
        }
        a = lo; b = old;
    }
}

// run index containing set bit p of mask m
__device__ __forceinline__ int runidx(unsigned m, int p) {
    unsigned starts = m & ~(m << 1);
    return __popc(starts & ((2u << p) - 1u)) - 1;
}

__device__ __forceinline__ int nruns(unsigned m) {
    return __popc(m & ~(m << 1));
}

// ---------- patch-local LDS union-find (ids: run_idx*512 + local_col) ----------
// path-halving: stores past-ancestor values only (monotone chains -> safe)
__device__ __forceinline__ unsigned luf_find(unsigned* su, unsigned x) {
    for (;;) {
        unsigned p = su[x];
        if (p == x) return x;
        unsigned g = su[p];
        if (g == p) return p;
        su[x] = g;
        x = g;
    }
}

__device__ __forceinline__ void luf_union(unsigned* su, unsigned a, unsigned b) {
    for (;;) {
        a = luf_find(su, a);
        b = luf_find(su, b);
        if (a == b) return;
        unsigned lo = a < b ? a : b;
        unsigned hi = a < b ? b : a;
        unsigned old = atomicMin(&su[hi], lo);
        if (old == hi) return;
        a = lo; b = old;
    }
}

// intra-patch unions for local col lc against right (+1) and down (+32) neighbors
__device__ __forceinline__ void punions(unsigned* su, const unsigned* sm,
                                        unsigned m, int lc, bool rok, bool dok) {
    if (!m) return;
    if (rok) {
        unsigned mB = sm[lc + 1];
        unsigned ov = m & mB;
        while (ov) {
            int p = __ffs(ov) - 1;
            luf_union(su, (unsigned)runidx(m, p) * LCOLS + lc,
                          (unsigned)runidx(mB, p) * LCOLS + lc + 1);
            ov &= ov + (1u << p);
        }
    }
    if (dok) {
        unsigned mB = sm[lc + 32];
        unsigned ov = m & mB;
        while (ov) {
            int p = __ffs(ov) - 1;
            luf_union(su, (unsigned)runidx(m, p) * LCOLS + lc,
                          (unsigned)runidx(mB, p) * LCOLS + lc + 32);
            ov &= ov + (1u << p);
        }
    }
}

// XCD-chunked block swizzles (verified r5): each XCD owns one batch's blocks,
// so producer/consumer data stays on the writing XCD's L2 and no 128B HBM
// line is fetched by two XCDs.
__device__ __forceinline__ int swz_blk(int d) {
    return (d % NXCD) * CHUNK + d / NXCD;
}
__device__ __forceinline__ int swz_bnd(int d) {
    return (d % NXCD) * CHUNK_BND + d / NXCD;
}

// ---------------- kernels ----------------

// x -> thresholds in-reg -> patch-local UF on weak masks; roots carry strong
// flag; writes weak-mask array (u16) and all parent1 entries
__global__ __launch_bounds__(256) void k_loc1(const float* __restrict__ x,
                                              unsigned short* __restrict__ weakm,
                                              unsigned* __restrict__ parent1) {
    __shared__ unsigned sm[512];
    __shared__ unsigned su[4096];          // 8 strata x 512 cols
    __shared__ unsigned char sf[4096];     // strong flag per local id
    int blk = swz_blk(blockIdx.x);
    int b = blk / (PHB * PWB), pr = blk % (PHB * PWB);
    int h0 = (pr / PWB) * PTH, w0 = (pr % PWB) * PTW;
    int t = threadIdx.x;
    int lw = t & 31, lh = t >> 5;
    unsigned m[2], st[2];
    #pragma unroll
    for (int k = 0; k < 2; ++k) {
        int r = lh + 8 * k;
        const float* xp = x + (size_t)b * DHW + (size_t)(h0 + r) * W_ + (w0 + lw);
        float vz[16];
        #pragma unroll
        for (int z = 0; z < 16; ++z) vz[z] = xp[(size_t)z * HW];
        unsigned mm = 0, ss = 0;
        #pragma unroll
        for (int z = 0; z < 16; ++z) {
            mm |= (vz[z] >= T_LOW  ? 1u : 0u) << z;
            ss |= (vz[z] >= T_HIGH ? 1u : 0u) << z;
        }
        m[k] = mm; st[k] = ss;
        weakm[b * HW + (h0 + r) * W_ + (w0 + lw)] = (unsigned short)mm;
        sm[r * 32 + lw] = mm;
    }
    #pragma unroll
    for (int i = 0; i < 16; ++i) su[i * 256 + t] = i * 256 + t;
    unsigned* sf32 = (unsigned*)sf;
    #pragma unroll
    for (int i = 0; i < 4; ++i) sf32[i * 256 + t] = 0;
    __syncthreads();
    #pragma unroll
    for (int k = 0; k < 2; ++k) {
        int r = lh + 8 * k, lc = r * 32 + lw;
        punions(su, sm, m[k], lc, lw < 31, r < 15);
    }
    __syncthreads();
    // strong-flag pass: iterate strong bits; group-clear dedupes within a run
    #pragma unroll
    for (int k = 0; k < 2; ++k) {
        unsigned ov = st[k];
        if (!ov) continue;
        int lc = (lh + 8 * k) * 32 + lw;
        while (ov) {
            int p = __ffs(ov) - 1;
            sf[luf_find(su, (unsigned)runidx(m[k], p) * LCOLS + lc)] = 1;
            ov &= ov + (1u << p);
        }
    }
    __syncthreads();
    #pragma unroll
    for (int k = 0; k < 2; ++k) {
        int r = lh + 8 * k, lc = r * 32 + lw;
        int c = b * HW + (h0 + r) * W_ + (w0 + lw);
        int nr = nruns(m[k]);
        for (int i = 0; i < nr; ++i) {
            unsigned lid = (unsigned)i * LCOLS + lc;
            unsigned lr  = luf_find(su, lid);
            unsigned gid = (unsigned)i * NCOL + c;
            if (lr == lid) parent1[gid] = sf[lid] ? FLAGGED : 0xFFFFFFFFu;
            else {
                unsigned tt = lr & (LCOLS - 1u), ss2 = lr >> 9;
                parent1[gid] = ss2 * NCOL +
                    (unsigned)(b * HW + (h0 + (int)(tt >> 5)) * W_ + (w0 + (int)(tt & 31)));
            }
        }
    }
}

// cross-patch boundary unions with flag propagation (weak).
// Serial-per-pair mapping: 64 lanes process 64 pairs' unions in lockstep.
// Batch-affinity swizzle: each XCD handles the batch its loc blocks wrote.
__global__ __launch_bounds__(256) void k_bnd1(const unsigned short* __restrict__ weakm,
                                              unsigned* parent1) {
    int e = swz_bnd(blockIdx.x) * 256 + threadIdx.x;
    int b = e / PAIR_B, r = e % PAIR_B;
    int cA, cB;
    if (r < WPAIR_B) {
        int h = r / (PWB - 1), wi = r % (PWB - 1);
        cA = b * HW + h * W_ + wi * PTW + (PTW - 1);
        cB = cA + 1;
    } else {
        r -= WPAIR_B;
        int hi = r / W_, w = r % W_;
        cA = b * HW + (hi * PTH + (PTH - 1)) * W_ + w;
        cB = cA + W_;
    }
    unsigned mA = weakm[cA];
    unsigned mB = weakm[cB];
    unsigned ov = mA & mB;
    while (ov) {
        int p = __ffs(ov) - 1;
        gunite_flag(parent1, (unsigned)runidx(mA, p) * NCOL + cA,
                             (unsigned)runidx(mB, p) * NCOL + cB);
        ov &= ov + (1u << p);
    }
}

// hysteresis (prefetched first-hop chase) + z-closing + patch-local UF on
// closed masks with per-local-root voxel counts; writes closed + parent2
__global__ __launch_bounds__(256) void k_loc2(const unsigned short* __restrict__ weakm,
                                              unsigned* parent1,
                                              unsigned short* __restrict__ closed,
                                              unsigned* __restrict__ parent2) {
    __shared__ unsigned sm[512];
    __shared__ unsigned su[3072];   // closed masks: <=6 runs/col (gaps >=2)
    __shared__ unsigned sc[3072];
    int blk = swz_blk(blockIdx.x);
    int b = blk / (PHB * PWB), pr = blk % (PHB * PWB);
    int h0 = (pr / PWB) * PTH, w0 = (pr % PWB) * PTW;
    int t = threadIdx.x;
    int lw = t & 31, lh = t >> 5;
    unsigned wk[2];
    int c_[2];
    #pragma unroll
    for (int k = 0; k < 2; ++k) {
        int r = lh + 8 * k;
        c_[k] = b * HW + (h0 + r) * W_ + (w0 + lw);
        wk[k] = weakm[c_[k]];
    }
    // prefetch first hop for up to 6 runs per col, both cols (12 independent loads)
    unsigned pv[2][6];
    #pragma unroll
    for (int k = 0; k < 2; ++k) {
        int nrw = nruns(wk[k]);
        #pragma unroll
        for (int i = 0; i < 6; ++i)
            if (i < nrw) pv[k][i] = parent1[(unsigned)i * NCOL + c_[k]];
    }
    unsigned ero[2];
    #pragma unroll
    for (int k = 0; k < 2; ++k) {
        unsigned m = 0;
        unsigned rem = wk[k]; int idx = 0;
        while (rem) {
            int p = __ffs(rem) - 1;
            unsigned tt = rem >> p;
            int len = __ffs(~tt) - 1;
            unsigned runmask = ((1u << len) - 1u) << p;
            unsigned rv;
            if (idx < 6) { unsigned v = pv[k][idx]; rv = (v >= NRUN) ? v : groot_val(parent1, v); }
            else rv = groot_val(parent1, (unsigned)idx * NCOL + c_[k]);
            if (rv == FLAGGED) m |= runmask;
            rem &= ~runmask; ++idx;
        }
        // z-closing: dilate (OOB = background), erode (OOB = foreground)
        unsigned dil = (m | (m << 1) | (m >> 1)) & 0xFFFFu;
        unsigned e = dil & ((dil << 1) | 1u) & ((dil >> 1) | 0x8000u);
        ero[k] = e;
        closed[c_[k]] = (unsigned short)e;
        sm[(lh + 8 * k) * 32 + lw] = e;
    }
    #pragma unroll
    for (int i = 0; i < 12; ++i) su[i * 256 + t] = i * 256 + t;
    #pragma unroll
    for (int i = 0; i < 12; ++i) sc[i * 256 + t] = 0;
    __syncthreads();
    #pragma unroll
    for (int k = 0; k < 2; ++k) {
        int r = lh + 8 * k, lc = r * 32 + lw;
        punions(su, sm, ero[k], lc, lw < 31, r < 15);
    }
    __syncthreads();
    #pragma unroll
    for (int k = 0; k < 2; ++k) {
        int lc = (lh + 8 * k) * 32 + lw;
        unsigned rem = ero[k]; int idx = 0;
        while (rem) {
            int p = __ffs(rem) - 1;
            unsigned tt = rem >> p;
            int len = __ffs(~tt) - 1;
            unsigned runmask = ((1u << len) - 1u) << p;
            atomicAdd(&sc[luf_find(su, (unsigned)idx * LCOLS + lc)], (unsigned)len);
            rem &= ~runmask; ++idx;
        }
    }
    __syncthreads();
    #pragma unroll
    for (int k = 0; k < 2; ++k) {
        int r = lh + 8 * k, lc = r * 32 + lw;
        int c = c_[k];
        int nr = nruns(ero[k]);
        for (int i = 0; i < nr; ++i) {
            unsigned lid = (unsigned)i * LCOLS + lc;
            unsigned lr  = luf_find(su, lid);
            unsigned gid = (unsigned)i * NCOL + c;
            if (lr == lid) parent2[gid] = 0xFFFFFFFFu - sc[lid];
            else {
                unsigned tt = lr & (LCOLS - 1u), ss2 = lr >> 9;
                parent2[gid] = ss2 * NCOL +
                    (unsigned)(b * HW + (h0 + (int)(tt >> 5)) * W_ + (w0 + (int)(tt & 31)));
            }
        }
    }
}

// cross-patch boundary unions with count propagation (closed)
__global__ __launch_bounds__(256) void k_bnd2(const unsigned short* __restrict__ closed,
                                              unsigned* parent2) {
    int e = swz_bnd(blockIdx.x) * 256 + threadIdx.x;
    int b = e / PAIR_B, r = e % PAIR_B;
    int cA, cB;
    if (r < WPAIR_B) {
        int h = r / (PWB - 1), wi = r % (PWB - 1);
        cA = b * HW + h * W_ + wi * PTW + (PTW - 1);
        cB = cA + 1;
    } else {
        r -= WPAIR_B;
        int hi = r / W_, w = r % W_;
        cA = b * HW + (hi * PTH + (PTH - 1)) * W_ + w;
        cB = cA + W_;
    }
    unsigned mA = closed[cA];
    unsigned mB = closed[cB];
    unsigned ov = mA & mB;
    while (ov) {
        int p = __ffs(ov) - 1;
        gunite_cnt(parent2, (unsigned)runidx(mA, p) * NCOL + cA,
                            (unsigned)runidx(mB, p) * NCOL + cB);
        ov &= ov + (1u << p);
    }
}

// keep components with size >= DUST_MIN; write 0/1 float (4 cols/thread)
__global__ __launch_bounds__(256) void k_out(const unsigned short* __restrict__ closed,
                                             unsigned* parent2,
                                             float* __restrict__ out) {
    int q = blockIdx.x * 256 + threadIdx.x;
    int c0 = q * 4;
    int b = c0 / HW, off = c0 - b * HW;
    ushort4 cc4 = *(const ushort4*)(closed + c0);
    unsigned fg[4] = {cc4.x, cc4.y, cc4.z, cc4.w};
    // closed masks have inter-run gaps >= 2 (erosion), so nruns <= 6:
    // prefetching 6 first-hops covers every run; fallback kept as guard only.
    unsigned pv[4][6];
    int nr[4];
    #pragma unroll
    for (int j = 0; j < 4; ++j) {
        nr[j] = nruns(fg[j]);
        #pragma unroll
        for (int i = 0; i < 6; ++i)
            if (i < nr[j]) pv[j][i] = parent2[(unsigned)i * NCOL + (c0 + j)];
    }
    unsigned keep[4];
    #pragma unroll
    for (int j = 0; j < 4; ++j) {
        int c = c0 + j;
        unsigned k = 0;
        unsigned rem = fg[j]; int idx = 0;
        while (rem) {
            int p = __ffs(rem) - 1;
            unsigned tt = rem >> p;
            int len = __ffs(~tt) - 1;
            unsigned runmask = ((1u << len) - 1u) << p;
            unsigned rv;
            if (idx < 6) { unsigned v = pv[j][idx]; rv = (v >= NRUN) ? v : groot_val(parent2, v); }
            else rv = groot_val(parent2, (unsigned)idx * NCOL + c);
            if (0xFFFFFFFFu - rv >= DUST_MIN) k |= runmask;
            rem &= ~runmask; ++idx;
        }
        keep[j] = k;
    }
    float* op = out + (size_t)b * DHW + off;
    #pragma unroll
    for (int z = 0; z < D_; ++z) {
        *(float4*)(op + (size_t)z * HW) =
            make_float4((keep[0] >> z) & 1u ? 1.0f : 0.0f,
                        (keep[1] >> z) & 1u ? 1.0f : 0.0f,
                        (keep[2] >> z) & 1u ? 1.0f : 0.0f,
                        (keep[3] >> z) & 1u ? 1.0f : 0.0f);
    }
}

extern "C" void kernel_launch(void* const* d_in, const int* in_sizes, int n_in,
                              void* d_out, int out_size, void* d_ws, size_t ws_size,
                              hipStream_t stream) {
    const float* x = (const float*)d_in[0];
    float* out = (float*)d_out;

    // ws: parent1 [NRUN u32] | parent2 [NRUN u32] | weak [NCOL u16] | closed [NCOL u16]
    const size_t sz_parent = (size_t)NRUN * 4;
    const size_t sz_mask   = (size_t)NCOL * 2;
    if (ws_size < 2 * sz_parent + 2 * sz_mask) return;
    char* ws = (char*)d_ws;
    unsigned*       parent1 = (unsigned*)ws;
    unsigned*       parent2 = (unsigned*)(ws + sz_parent);
    unsigned short* weakm   = (unsigned short*)(ws + 2 * sz_parent);
    unsigned short* closed  = (unsigned short*)(ws + 2 * sz_parent + sz_mask);

    dim3 blk(256);
    dim3 grdL(NPATCH), grdB(NBLK_BND), grdQ(NBLK_QUAD);

    // ---- phase 1: weak-run CCL with inline strong flags ----
    k_loc1<<<grdL, blk, 0, stream>>>(x, weakm, parent1);
    k_bnd1<<<grdB, blk, 0, stream>>>(weakm, parent1);

    // ---- phase 2: hysteresis+closing, closed-run CCL with inline counts ----
    k_loc2<<<grdL, blk, 0, stream>>>(weakm, parent1, closed, parent2);
    k_bnd2<<<grdB, blk, 0, stream>>>(closed, parent2);
    k_out<<<grdQ, blk, 0, stream>>>(closed, parent2, out);
}

// Round 9
// 245.374 us; speedup vs baseline: 1.2851x; 1.0532x over previous
//
#include <hip/hip_runtime.h>
#include <stdint.h>

// Fixed problem shape: outputs [8,16,384,384] fp32
#define B_ 8
#define D_ 16
#define H_ 384
#define W_ 384
constexpr int HW   = H_ * W_;     // 147456
constexpr int DHW  = D_ * HW;     // 2359296
constexpr int NCOL = B_ * HW;     // 1179648 columns
// Stratified run ids: id = run_idx * NCOL + column (runs concentrate in strata 0..2)
constexpr unsigned NRUN = (unsigned)NCOL * 8u;

constexpr float T_LOW  = 0.8f;
constexpr float T_HIGH = 0.92f;
constexpr unsigned DUST_MIN = 20u;
constexpr unsigned FLAGGED = 0xFFFFFFFEu;   // phase-1 root value: has strong voxel

constexpr int NBLK_QUAD = NCOL / 1024;  // 1152 (4 cols/thread kernels)

// local-UF patches: 16x16 cols (r5 optimum: 1 col/thread; 2 and 4 cols/thread
// measured +18/+42 us on k_loc1 — serial divergent chains scale superlinearly)
constexpr int PTW = 16, PTH = 16;
constexpr int PWB = W_ / PTW;             // 24
constexpr int PHB = H_ / PTH;             // 24
constexpr int NPATCH = B_ * PWB * PHB;    // 4608
constexpr int NXCD = 8;
constexpr int CHUNK = NPATCH / NXCD;      // 576 = exactly one batch's patches

// boundary column-pairs between patches
constexpr int WPAIR_B = (PWB - 1) * H_;      // 8832
constexpr int HPAIR_B = (PHB - 1) * W_;      // 8832
constexpr int PAIR_B  = WPAIR_B + HPAIR_B;   // 17664
constexpr int NPAIRS  = B_ * PAIR_B;         // 141312
constexpr int NBLK_BND  = NPAIRS / 256;      // 552 (exact)
constexpr int CHUNK_BND = NBLK_BND / NXCD;   // 69 = one batch's pair-blocks
constexpr int CHUNK_OUT = NBLK_QUAD / NXCD;  // 144 = one batch's out-blocks

// ---------- global union-find over stratified z-run ids ----------
// parent[] : value < NRUN -> parent pointer; value >= NRUN -> root encoding.
// Phase 1 roots: 0xFFFFFFFF = no strong, 0xFFFFFFFE = has strong.
// Phase 2 roots: 0xFFFFFFFF - componentVoxelCount.
// Parents only ever decrease; halving stores only past-ancestor pointers (safe).
__device__ __forceinline__ unsigned gfind(unsigned* A, unsigned x) {
    for (;;) {
        unsigned p = A[x];
        if (p >= NRUN) return x;
        unsigned g = A[p];
        if (g >= NRUN) return p;
        A[x] = g;
        x = g;
    }
}

__device__ __forceinline__ unsigned groot_val(unsigned* A, unsigned x) {
    for (;;) {
        unsigned p = A[x];
        if (p >= NRUN) return p;
        unsigned g = A[p];
        if (g >= NRUN) return g;
        A[x] = g;
        x = g;
    }
}

// ensure the root of x's component is flagged (phase 1)
__device__ __forceinline__ void set_flag(unsigned* A, unsigned x) {
    unsigned r = gfind(A, x);
    for (;;) {
        unsigned old = atomicMin(&A[r], FLAGGED);
        if (old >= NRUN) return;
        r = gfind(A, old);
    }
}

// add cnt into the root encoding of x's component (phase 2).
__device__ __forceinline__ void add_count(unsigned* A, unsigned x, unsigned cnt) {
    unsigned r = gfind(A, x);
    for (;;) {
        unsigned old = A[r];
        if (old < NRUN) { r = gfind(A, old); continue; }
        if (atomicCAS(&A[r], old, old - cnt) == old) return;
    }
}

// union with flag propagation (phase 1)
__device__ __forceinline__ void gunite_flag(unsigned* A, unsigned a, unsigned b) {
    for (;;) {
        a = gfind(A, a);
        b = gfind(A, b);
        if (a == b) return;
        unsigned lo = a < b ? a : b;
        unsigned hi = a < b ? b : a;
        unsigned old = atomicMin(&A[hi], lo);
        if (old >= NRUN) {
            if (old == FLAGGED) set_flag(A, lo);
            return;
        }
        a = lo; b = old;
    }
}

// union with count propagation (phase 2)
__device__ __forceinline__ void gunite_cnt(unsigned* A, unsigned a, unsigned b) {
    for (;;) {
        a = gfind(A, a);
        b = gfind(A, b);
        if (a == b) return;
        unsigned lo = a < b ? a : b;
        unsigned hi = a < b ? b : a;
        unsigned old = atomicMin(&A[hi], lo);
        if (old >= NRUN) {
            unsigned cnt = 0xFFFFFFFFu - old;
            if (cnt) add_count(A, lo, cnt);
            return;
        }
        a = lo; b = old;
    }
}

// run index containing set bit p of mask m
__device__ __forceinline__ int runidx(unsigned m, int p) {
    unsigned starts = m & ~(m << 1);
    return __popc(starts & ((2u << p) - 1u)) - 1;
}

__device__ __forceinline__ int nruns(unsigned m) {
    return __popc(m & ~(m << 1));
}

// ---------- patch-local LDS union-find (ids: run_idx*256 + thread) ----------
// path-halving: stores past-ancestor values only (monotone chains -> safe)
__device__ __forceinline__ unsigned luf_find(unsigned* su, unsigned x) {
    for (;;) {
        unsigned p = su[x];
        if (p == x) return x;
        unsigned g = su[p];
        if (g == p) return p;
        su[x] = g;
        x = g;
    }
}

__device__ __forceinline__ void luf_union(unsigned* su, unsigned a, unsigned b) {
    for (;;) {
        a = luf_find(su, a);
        b = luf_find(su, b);
        if (a == b) return;
        unsigned lo = a < b ? a : b;
        unsigned hi = a < b ? b : a;
        unsigned old = atomicMin(&su[hi], lo);
        if (old == hi) return;
        a = lo; b = old;
    }
}

// intra-patch unions for column t against neighbors t+1, t+16 (masks in sm)
// 16x16 patch: lw = t&15, lh = t>>4
__device__ __forceinline__ void patch_unions(unsigned* su, const unsigned* sm,
                                             unsigned m, int t) {
    int lw = t & 15, lh = t >> 4;
    if (!m) return;
    if (lw < 15) {
        unsigned mB = sm[t + 1];
        unsigned ov = m & mB;
        while (ov) {
            int p = __ffs(ov) - 1;
            luf_union(su, (unsigned)runidx(m, p) * 256 + t,
                          (unsigned)runidx(mB, p) * 256 + t + 1);
            ov &= ov + (1u << p);
        }
    }
    if (lh < 15) {
        unsigned mB = sm[t + 16];
        unsigned ov = m & mB;
        while (ov) {
            int p = __ffs(ov) - 1;
            luf_union(su, (unsigned)runidx(m, p) * 256 + t,
                          (unsigned)runidx(mB, p) * 256 + t + 16);
            ov &= ov + (1u << p);
        }
    }
}

// XCD-chunked swizzles (r5 verified): dispatch id d goes to XCD d%8; the remap
// gives XCD i a contiguous chunk = exactly batch i's blocks, so every kernel's
// reads/atomics on that batch's masks/parents hit the L2 that wrote them.
__device__ __forceinline__ int swz_blk(int d) {
    return (d % NXCD) * CHUNK + d / NXCD;
}
__device__ __forceinline__ int swz_bnd(int d) {
    return (d % NXCD) * CHUNK_BND + d / NXCD;
}
__device__ __forceinline__ int swz_out(int d) {
    return (d % NXCD) * CHUNK_OUT + d / NXCD;
}

// ---------------- kernels ----------------

// x -> thresholds in-reg -> patch-local UF on weak masks; roots carry strong
// flag; writes weak-mask array (u16) and all parent1 entries
__global__ __launch_bounds__(256) void k_loc1(const float* __restrict__ x,
                                              unsigned short* __restrict__ weakm,
                                              unsigned* __restrict__ parent1) {
    __shared__ unsigned sm[256];
    __shared__ unsigned su[2048];
    __shared__ unsigned sf[2048];
    int blk = swz_blk(blockIdx.x);
    int b = blk / (PHB * PWB), pr = blk % (PHB * PWB);
    int h0 = (pr / PWB) * PTH, w0 = (pr % PWB) * PTW;
    int t = threadIdx.x;
    int c = b * HW + (h0 + (t >> 4)) * W_ + (w0 + (t & 15));
    const float* xp = x + (size_t)b * DHW + (size_t)(h0 + (t >> 4)) * W_ + (w0 + (t & 15));
    float vz[16];
    #pragma unroll
    for (int z = 0; z < 16; ++z) vz[z] = xp[(size_t)z * HW];   // 16 independent loads
    unsigned m = 0, st = 0;
    #pragma unroll
    for (int z = 0; z < 16; ++z) {
        m  |= (vz[z] >= T_LOW  ? 1u : 0u) << z;
        st |= (vz[z] >= T_HIGH ? 1u : 0u) << z;
    }
    weakm[c] = (unsigned short)m;
    sm[t] = m;
    #pragma unroll
    for (int i = 0; i < 8; ++i) { su[i * 256 + t] = i * 256 + t; sf[i * 256 + t] = 0; }
    __syncthreads();
    patch_unions(su, sm, m, t);
    __syncthreads();
    // strong-flag pass: iterate strong bits (avg 1.3/col) instead of decoding
    // every weak run; group-clear dedupes contiguous strong bits within a run.
    if (st) {
        unsigned ov = st;
        while (ov) {
            int p = __ffs(ov) - 1;
            sf[luf_find(su, (unsigned)runidx(m, p) * 256 + t)] = 1u;
            ov &= ov + (1u << p);
        }
    }
    __syncthreads();
    int nr = nruns(m);
    for (int i = 0; i < nr; ++i) {
        unsigned lid = (unsigned)i * 256 + t;
        unsigned lr  = luf_find(su, lid);
        unsigned gid = (unsigned)i * NCOL + c;
        if (lr == lid) parent1[gid] = sf[lid] ? FLAGGED : 0xFFFFFFFFu;
        else {
            unsigned tt = lr & 255u, ss = lr >> 8;
            parent1[gid] = ss * NCOL +
                (unsigned)(b * HW + (h0 + (int)(tt >> 4)) * W_ + (w0 + (int)(tt & 15)));
        }
    }
}

// cross-patch boundary unions with flag propagation (weak).
// Serial-per-pair mapping; batch-affinity swizzle keeps every gfind load and
// atomicMin on the XCD whose loc blocks wrote that batch's data.
__global__ __launch_bounds__(256) void k_bnd1(const unsigned short* __restrict__ weakm,
                                              unsigned* parent1) {
    int e = swz_bnd(blockIdx.x) * 256 + threadIdx.x;
    int b = e / PAIR_B, r = e % PAIR_B;
    int cA, cB;
    if (r < WPAIR_B) {
        int h = r / (PWB - 1), wi = r % (PWB - 1);
        cA = b * HW + h * W_ + wi * PTW + (PTW - 1);
        cB = cA + 1;
    } else {
        r -= WPAIR_B;
        int hi = r / W_, w = r % W_;
        cA = b * HW + (hi * PTH + (PTH - 1)) * W_ + w;
        cB = cA + W_;
    }
    unsigned mA = weakm[cA];
    unsigned mB = weakm[cB];
    unsigned ov = mA & mB;
    while (ov) {
        int p = __ffs(ov) - 1;
        gunite_flag(parent1, (unsigned)runidx(mA, p) * NCOL + cA,
                             (unsigned)runidx(mB, p) * NCOL + cB);
        ov &= ov + (1u << p);
    }
}

// hysteresis (prefetched first-hop chase) + z-closing + patch-local UF on
// closed masks with per-local-root voxel counts; writes closed + parent2
__global__ __launch_bounds__(256) void k_loc2(const unsigned short* __restrict__ weakm,
                                              unsigned* parent1,
                                              unsigned short* __restrict__ closed,
                                              unsigned* __restrict__ parent2) {
    __shared__ unsigned sm[256];
    __shared__ unsigned su[2048];
    __shared__ unsigned sc[2048];
    int blk = swz_blk(blockIdx.x);
    int b = blk / (PHB * PWB), pr = blk % (PHB * PWB);
    int h0 = (pr / PWB) * PTH, w0 = (pr % PWB) * PTW;
    int t = threadIdx.x;
    int c = b * HW + (h0 + (t >> 4)) * W_ + (w0 + (t & 15));
    unsigned wk = weakm[c];
    int nrw = nruns(wk);
    // prefetch first hop for up to 6 runs (independent, predicated loads)
    unsigned pv[6];
    #pragma unroll
    for (int i = 0; i < 6; ++i) if (i < nrw) pv[i] = parent1[(unsigned)i * NCOL + c];
    unsigned m = 0;
    {
        unsigned rem = wk; int idx = 0;
        while (rem) {
            int p = __ffs(rem) - 1;
            unsigned tt = rem >> p;
            int len = __ffs(~tt) - 1;
            unsigned runmask = ((1u << len) - 1u) << p;
            unsigned rv;
            if (idx < 6) { unsigned v = pv[idx]; rv = (v >= NRUN) ? v : groot_val(parent1, v); }
            else rv = groot_val(parent1, (unsigned)idx * NCOL + c);
            if (rv == FLAGGED) m |= runmask;
            rem &= ~runmask; ++idx;
        }
    }
    // z-closing: dilate (OOB = background), erode (OOB = foreground)
    unsigned dil = (m | (m << 1) | (m >> 1)) & 0xFFFFu;
    unsigned ero = dil & ((dil << 1) | 1u) & ((dil >> 1) | 0x8000u);
    closed[c] = (unsigned short)ero;

    sm[t] = ero;
    #pragma unroll
    for (int i = 0; i < 8; ++i) { su[i * 256 + t] = i * 256 + t; sc[i * 256 + t] = 0; }
    __syncthreads();
    patch_unions(su, sm, ero, t);
    __syncthreads();
    {
        unsigned rem = ero; int idx = 0;
        while (rem) {
            int p = __ffs(rem) - 1;
            unsigned tt = rem >> p;
            int len = __ffs(~tt) - 1;
            unsigned runmask = ((1u << len) - 1u) << p;
            atomicAdd(&sc[luf_find(su, (unsigned)idx * 256 + t)], (unsigned)len);
            rem &= ~runmask; ++idx;
        }
    }
    __syncthreads();
    int nr = nruns(ero);
    for (int i = 0; i < nr; ++i) {
        unsigned lid = (unsigned)i * 256 + t;
        unsigned lr  = luf_find(su, lid);
        unsigned gid = (unsigned)i * NCOL + c;
        if (lr == lid) parent2[gid] = 0xFFFFFFFFu - sc[lid];
        else {
            unsigned tt = lr & 255u, ss = lr >> 8;
            parent2[gid] = ss * NCOL +
                (unsigned)(b * HW + (h0 + (int)(tt >> 4)) * W_ + (w0 + (int)(tt & 15)));
        }
    }
}

// cross-patch boundary unions with count propagation (closed); batch-affinity swizzle
__global__ __launch_bounds__(256) void k_bnd2(const unsigned short* __restrict__ closed,
                                              unsigned* parent2) {
    int e = swz_bnd(blockIdx.x) * 256 + threadIdx.x;
    int b = e / PAIR_B, r = e % PAIR_B;
    int cA, cB;
    if (r < WPAIR_B) {
        int h = r / (PWB - 1), wi = r % (PWB - 1);
        cA = b * HW + h * W_ + wi * PTW + (PTW - 1);
        cB = cA + 1;
    } else {
        r -= WPAIR_B;
        int hi = r / W_, w = r % W_;
        cA = b * HW + (hi * PTH + (PTH - 1)) * W_ + w;
        cB = cA + W_;
    }
    unsigned mA = closed[cA];
    unsigned mB = closed[cB];
    unsigned ov = mA & mB;
    while (ov) {
        int p = __ffs(ov) - 1;
        gunite_cnt(parent2, (unsigned)runidx(mA, p) * NCOL + cA,
                            (unsigned)runidx(mB, p) * NCOL + cB);
        ov &= ov + (1u << p);
    }
}

// keep components with size >= DUST_MIN; write 0/1 float (4 cols/thread);
// batch-affinity swizzle (144 blocks/batch exact)
__global__ __launch_bounds__(256) void k_out(const unsigned short* __restrict__ closed,
                                             unsigned* parent2,
                                             float* __restrict__ out) {
    int q = swz_out(blockIdx.x) * 256 + threadIdx.x;
    int c0 = q * 4;
    int b = c0 / HW, off = c0 - b * HW;
    ushort4 cc4 = *(const ushort4*)(closed + c0);
    unsigned fg[4] = {cc4.x, cc4.y, cc4.z, cc4.w};
    // closed masks have inter-run gaps >= 2 (erosion), so nruns <= 6:
    // prefetching 6 first-hops covers every run; fallback kept as guard only.
    unsigned pv[4][6];
    int nr[4];
    #pragma unroll
    for (int j = 0; j < 4; ++j) {
        nr[j] = nruns(fg[j]);
        #pragma unroll
        for (int i = 0; i < 6; ++i)
            if (i < nr[j]) pv[j][i] = parent2[(unsigned)i * NCOL + (c0 + j)];
    }
    unsigned keep[4];
    #pragma unroll
    for (int j = 0; j < 4; ++j) {
        int c = c0 + j;
        unsigned k = 0;
        unsigned rem = fg[j]; int idx = 0;
        while (rem) {
            int p = __ffs(rem) - 1;
            unsigned tt = rem >> p;
            int len = __ffs(~tt) - 1;
            unsigned runmask = ((1u << len) - 1u) << p;
            unsigned rv;
            if (idx < 6) { unsigned v = pv[j][idx]; rv = (v >= NRUN) ? v : groot_val(parent2, v); }
            else rv = groot_val(parent2, (unsigned)idx * NCOL + c);
            if (0xFFFFFFFFu - rv >= DUST_MIN) k |= runmask;
            rem &= ~runmask; ++idx;
        }
        keep[j] = k;
    }
    float* op = out + (size_t)b * DHW + off;
    #pragma unroll
    for (int z = 0; z < D_; ++z) {
        *(float4*)(op + (size_t)z * HW) =
            make_float4((keep[0] >> z) & 1u ? 1.0f : 0.0f,
                        (keep[1] >> z) & 1u ? 1.0f : 0.0f,
                        (keep[2] >> z) & 1u ? 1.0f : 0.0f,
                        (keep[3] >> z) & 1u ? 1.0f : 0.0f);
    }
}

extern "C" void kernel_launch(void* const* d_in, const int* in_sizes, int n_in,
                              void* d_out, int out_size, void* d_ws, size_t ws_size,
                              hipStream_t stream) {
    const float* x = (const float*)d_in[0];
    float* out = (float*)d_out;

    // ws: parent1 [NRUN u32] | parent2 [NRUN u32] | weak [NCOL u16] | closed [NCOL u16]
    const size_t sz_parent = (size_t)NRUN * 4;
    const size_t sz_mask   = (size_t)NCOL * 2;
    if (ws_size < 2 * sz_parent + 2 * sz_mask) return;
    char* ws = (char*)d_ws;
    unsigned*       parent1 = (unsigned*)ws;
    unsigned*       parent2 = (unsigned*)(ws + sz_parent);
    unsigned short* weakm   = (unsigned short*)(ws + 2 * sz_parent);
    unsigned short* closed  = (unsigned short*)(ws + 2 * sz_parent + sz_mask);

    dim3 blk(256);
    dim3 grdL(NPATCH), grdB(NBLK_BND), grdQ(NBLK_QUAD);

    // ---- phase 1: weak-run CCL with inline strong flags ----
    k_loc1<<<grdL, blk, 0, stream>>>(x, weakm, parent1);
    k_bnd1<<<grdB, blk, 0, stream>>>(weakm, parent1);

    // ---- phase 2: hysteresis+closing, closed-run CCL with inline counts ----
    k_loc2<<<grdL, blk, 0, stream>>>(weakm, parent1, closed, parent2);
    k_bnd2<<<grdB, blk, 0, stream>>>(closed, parent2);
    k_out<<<grdQ, blk, 0, stream>>>(closed, parent2, out);
}